// Round 22
// baseline (124.221 us; speedup 1.0000x reference)
//
#include <hip/hip_runtime.h>
#include <cmath>

#define EPSF 1e-6f
#define LDK 72   // padded stride: conflict-free ds_read_b128 fragments

// ---------------------------------------------------------------------------
// Shapes: B=1, S=2048, H=16, D=64, hid=1024
// R19 = 119.7us (8 launches; boundary cost ~2.5-4us each).
// R20: fuse eg_fin into fine_mfma (per-block EP from H1; x16 h-redundant but
// L2-fed and cheap). 8 -> 7 launches. All else bit-identical to R19.
// ---------------------------------------------------------------------------

typedef __attribute__((ext_vector_type(8))) short bf16x8;
typedef __attribute__((ext_vector_type(4))) float f32x4;
typedef __attribute__((ext_vector_type(8))) unsigned short u16x8;

__device__ __forceinline__ float wave_allsum(float v) {
#pragma unroll
  for (int off = 32; off > 0; off >>= 1) v += __shfl_xor(v, off, 64);
  return v;
}

__device__ __forceinline__ unsigned short f2bf(float f) {  // RNE f32->bf16
  unsigned int u = __float_as_uint(f);
  unsigned int r = (u + 0x7fffu + ((u >> 16) & 1u)) >> 16;
  return (unsigned short)r;
}
__device__ __forceinline__ float bf2f(unsigned short u) {
  return __uint_as_float(((unsigned int)u) << 16);
}

// ---------------- mega-prep: all input casts in one launch ------------------
__global__ __launch_bounds__(256) void prep_kernel(const float* __restrict__ FM,
    const float* __restrict__ FN, const float* __restrict__ HS,
    const float* __restrict__ W0, const float* __restrict__ W1,
    const float* __restrict__ W2, const float* __restrict__ W3,
    const float* __restrict__ EGW1,
    unsigned short* __restrict__ MCT, float* __restrict__ ZC,
    unsigned short* __restrict__ T0, unsigned short* __restrict__ T1,
    unsigned short* __restrict__ T2, unsigned short* __restrict__ T3,
    unsigned short* __restrict__ W1T, unsigned short* __restrict__ FMT,
    unsigned short* __restrict__ HSB)
{
  int b = blockIdx.x, tid = threadIdx.x;
  __shared__ float tile[64][65];
  if (b < 64) {
    int h = b >> 2, q = b & 3;
    for (int i = tid; i < 1024; i += 256) {
      int dpl = i >> 6, e = i & 63;
      int idx = (q * 16 + dpl) * 64 + e;
      tile[dpl][e] = FM[(0 * 16 + h) * 4096 + idx] + FM[(1 * 16 + h) * 4096 + idx]
                   + FM[(2 * 16 + h) * 4096 + idx] + FM[(3 * 16 + h) * 4096 + idx];
    }
    if (q == 0 && tid < 64)
      ZC[h * 64 + tid] = FN[h * 64 + tid] + FN[1024 + h * 64 + tid]
                       + FN[2048 + h * 64 + tid] + FN[3072 + h * 64 + tid];
    __syncthreads();
    for (int i = tid; i < 1024; i += 256) {
      int e = i >> 4, dpl = i & 15;
      MCT[h * 4096 + e * 64 + q * 16 + dpl] = f2bf(tile[dpl][e]);
    }
  } else if (b < 1088) {
    int r0 = b - 64, z = r0 >> 8, rem = r0 & 255;
    const float* W = (z == 0) ? W0 : (z == 1) ? W1 : (z == 2) ? W2 : W3;
    unsigned short* WT = (z == 0) ? T0 : (z == 1) ? T1 : (z == 2) ? T2 : T3;
    int n0 = (rem & 15) * 64, k0 = (rem >> 4) * 64;
    for (int i = tid; i < 4096; i += 256) {
      int r = i >> 6, c = i & 63;
      tile[r][c] = W[(k0 + r) * 1024 + n0 + c];
    }
    __syncthreads();
    for (int i = tid; i < 1024; i += 256) {
      int r = i >> 4, c4 = (i & 15) * 4;
      ushort4 o;
      o.x = f2bf(tile[c4 + 0][r]); o.y = f2bf(tile[c4 + 1][r]);
      o.z = f2bf(tile[c4 + 2][r]); o.w = f2bf(tile[c4 + 3][r]);
      *reinterpret_cast<ushort4*>(&WT[(n0 + r) * 1024 + k0 + c4]) = o;
    }
  } else if (b < 1152) {
    int rem = b - 1088;
    int n0 = (rem & 3) * 64, k0 = (rem >> 2) * 64;
    for (int i = tid; i < 4096; i += 256) {
      int r = i >> 6, c = i & 63;
      tile[r][c] = EGW1[(k0 + r) * 256 + n0 + c];
    }
    __syncthreads();
    for (int i = tid; i < 1024; i += 256) {
      int r = i >> 4, c4 = (i & 15) * 4;
      ushort4 o;
      o.x = f2bf(tile[c4 + 0][r]); o.y = f2bf(tile[c4 + 1][r]);
      o.z = f2bf(tile[c4 + 2][r]); o.w = f2bf(tile[c4 + 3][r]);
      *reinterpret_cast<ushort4*>(&W1T[(n0 + r) * 1024 + k0 + c4]) = o;
    }
  } else if (b < 1216) {
    int mat = b - 1152;
    const float* src = FM + mat * 4096;
    for (int i = tid; i < 4096; i += 256) tile[i >> 6][i & 63] = src[i];
    __syncthreads();
    unsigned short* dst = FMT + mat * 4096;
    for (int i = tid; i < 4096; i += 256) {
      int e = i >> 6, dp = i & 63;
      dst[e * 64 + dp] = f2bf(tile[dp][e]);
    }
  } else {
    int i = (b - 1216) * 256 + tid;
    float4 v = *reinterpret_cast<const float4*>(HS + i * 4);
    ushort4 o; o.x = f2bf(v.x); o.y = f2bf(v.y); o.z = f2bf(v.z); o.w = f2bf(v.w);
    *reinterpret_cast<ushort4*>(HSB + i * 4) = o;
  }
}

// fused QKV projections -> bf16
__global__ __launch_bounds__(256) void proj_bf16(const unsigned short* __restrict__ A,
    const unsigned short* __restrict__ WqT, const unsigned short* __restrict__ WkT,
    const unsigned short* __restrict__ WvT,
    unsigned short* __restrict__ Oq, unsigned short* __restrict__ Ok,
    unsigned short* __restrict__ Ov)
{
  int z = blockIdx.z;
  const unsigned short* BT = (z == 0) ? WqT : (z == 1) ? WkT : WvT;
  unsigned short* C = (z == 0) ? Oq : (z == 1) ? Ok : Ov;

  __shared__ unsigned short As[128 * LDK];
  __shared__ unsigned short Bs[128 * LDK];
  int tid = threadIdx.x;
  int m0 = blockIdx.y * 128, n0 = blockIdx.x * 128;
  int wid = tid >> 6, lane = tid & 63;
  int wr = wid >> 1, wc = wid & 1;
  int lr = lane & 15, lg = lane >> 4;
  int act = (z < 2) ? 1 : 0;

  f32x4 acc[4][4];
#pragma unroll
  for (int m = 0; m < 4; ++m)
#pragma unroll
    for (int n = 0; n < 4; ++n)
#pragma unroll
      for (int r = 0; r < 4; ++r) acc[m][n][r] = 0.f;

  for (int kt = 0; kt < 16; ++kt) {
    int k0 = kt * 64;
#pragma unroll
    for (int p = 0; p < 4; ++p) {
      int c = p * 256 + tid;
      int row = c >> 3, k8 = c & 7;
      u16x8 va = *reinterpret_cast<const u16x8*>(A + (m0 + row) * 1024 + k0 + k8 * 8);
      *reinterpret_cast<u16x8*>(&As[row * LDK + k8 * 8]) = va;
      u16x8 vb = *reinterpret_cast<const u16x8*>(BT + (n0 + row) * 1024 + k0 + k8 * 8);
      *reinterpret_cast<u16x8*>(&Bs[row * LDK + k8 * 8]) = vb;
    }
    __syncthreads();
#pragma unroll
    for (int kk = 0; kk < 2; ++kk) {
      bf16x8 af[4], bfr[4];
#pragma unroll
      for (int m = 0; m < 4; ++m)
        af[m] = *reinterpret_cast<const bf16x8*>(&As[(wr * 64 + m * 16 + lr) * LDK + kk * 32 + lg * 8]);
#pragma unroll
      for (int n = 0; n < 4; ++n)
        bfr[n] = *reinterpret_cast<const bf16x8*>(&Bs[(wc * 64 + n * 16 + lr) * LDK + kk * 32 + lg * 8]);
#pragma unroll
      for (int m = 0; m < 4; ++m)
#pragma unroll
        for (int n = 0; n < 4; ++n)
          acc[m][n] = __builtin_amdgcn_mfma_f32_16x16x32_bf16(af[m], bfr[n], acc[m][n], 0, 0, 0);
    }
    __syncthreads();
  }
#pragma unroll
  for (int m = 0; m < 4; ++m)
#pragma unroll
    for (int n = 0; n < 4; ++n)
#pragma unroll
      for (int r = 0; r < 4; ++r) {
        float v = acc[m][n][r];
        if (act) v = v > 0.f ? v + 1.f : expf(v);
        C[(m0 + wr * 64 + m * 16 + lg * 4 + r) * 1024 + n0 + wc * 64 + n * 16 + lr] = f2bf(v);
      }
}

// ---------------- mid1: rels [0,512) || chunk_mfma [512,1024) ---------------
__global__ __launch_bounds__(256) void mid1_kernel(const unsigned short* __restrict__ SQB,
    const float* __restrict__ ZC, const float* __restrict__ FN,
    const unsigned short* __restrict__ SKB, const unsigned short* __restrict__ VVB,
    float* __restrict__ RELC, float* __restrict__ RELS, float* __restrict__ PARTS,
    float* __restrict__ ST)
{
  __shared__ __align__(16) char smem[20736];
  int b = blockIdx.x, tid = threadIdx.x;
  if (b < 512) {
    int h = b >> 5, st = b & 31;
    int s0 = st * 64;
    float (*sqT)[68] = (float(*)[68])smem;
    float (*zf)[64]  = (float(*)[64])(smem + 17408);
    float (*relb)[64]= (float(*)[64])(smem + 18688);
#pragma unroll
    for (int p = 0; p < 2; ++p) {
      int cidx = p * 256 + tid;
      int r = cidx >> 3, d8 = cidx & 7;
      u16x8 v = *reinterpret_cast<const u16x8*>(SQB + (s0 + r) * 1024 + h * 64 + d8 * 8);
#pragma unroll
      for (int j = 0; j < 8; ++j) sqT[d8 * 8 + j][r] = bf2f((unsigned short)v[j]);
    }
    for (int idx = tid; idx < 320; idx += 256) {
      int w = idx >> 6, d = idx & 63;
      zf[w][d] = (w == 0) ? ZC[h * 64 + d] : FN[(w - 1) * 1024 + h * 64 + d];
    }
    __syncthreads();
    {
      int s = tid & 63, wh = tid >> 6;
      float r = 0.f;
      for (int dp = 0; dp < 64; ++dp) r += sqT[dp][s] * zf[wh][dp];
      relb[wh][s] = r;
      if (wh == 0) {
        float r4 = 0.f;
        for (int dp = 0; dp < 64; ++dp) r4 += sqT[dp][s] * zf[4][dp];
        relb[4][s] = r4;
      }
    }
    __syncthreads();
    if (tid < 64) {
      RELC[h * 2048 + s0 + tid] = relb[0][tid];
#pragma unroll
      for (int f = 0; f < 4; ++f)
        RELS[f * 32768 + h * 2048 + s0 + tid] = relb[1 + f][tid];
#pragma unroll
      for (int f = 0; f < 4; ++f) {
        float v = wave_allsum(relb[1 + f][tid]);
        if (tid == 0) PARTS[f * 512 + h * 32 + st] = v;
      }
    }
  } else {
    int bb = b - 512;
    int h = bb >> 5, c = bb & 31;
    int w = tid >> 6, lane = tid & 63, lr = lane & 15, lg = lane >> 4;
    int sb = c * 64;
    unsigned short* A_lds = (unsigned short*)smem;
    unsigned short* B_lds = (unsigned short*)(smem + 9216);
#pragma unroll
    for (int p = 0; p < 2; ++p) {
      int cc = p * 256 + tid;
      int t = cc >> 3, e8 = cc & 7;
      u16x8 kv = *reinterpret_cast<const u16x8*>(SKB + (sb + t) * 1024 + h * 64 + e8 * 8);
      u16x8 vv = *reinterpret_cast<const u16x8*>(VVB + (sb + t) * 1024 + h * 64 + e8 * 8);
#pragma unroll
      for (int j = 0; j < 8; ++j) {
        A_lds[(e8 * 8 + j) * LDK + t] = (unsigned short)kv[j];
        B_lds[(e8 * 8 + j) * LDK + t] = (unsigned short)vv[j];
      }
    }
    if (tid < 64) B_lds[64 * LDK + tid] = 0x3F80;
    for (int i = tid; i < 15 * 64; i += 256) {
      int row = 65 + (i >> 6), col = i & 63;
      B_lds[row * LDK + col] = 0;
    }
    __syncthreads();

    f32x4 acc[5];
#pragma unroll
    for (int n = 0; n < 5; ++n)
#pragma unroll
      for (int r = 0; r < 4; ++r) acc[n][r] = 0.f;
#pragma unroll
    for (int kk = 0; kk < 2; ++kk) {
      bf16x8 af = *reinterpret_cast<const bf16x8*>(&A_lds[(w * 16 + lr) * LDK + kk * 32 + lg * 8]);
#pragma unroll
      for (int n = 0; n < 5; ++n) {
        bf16x8 bfr = *reinterpret_cast<const bf16x8*>(&B_lds[(n * 16 + lr) * LDK + kk * 32 + lg * 8]);
        acc[n] = __builtin_amdgcn_mfma_f32_16x16x32_bf16(af, bfr, acc[n], 0, 0, 0);
      }
    }
    float* base = ST + (h * 32 + c) * 4160;
#pragma unroll
    for (int r = 0; r < 4; ++r) {
      int d = w * 16 + lg * 4 + r;
#pragma unroll
      for (int n = 0; n < 4; ++n)
        base[d * 64 + n * 16 + lr] = acc[n][r];
      if (lr == 0) base[4096 + d] = acc[4][r];
    }
  }
}

// ---------------- mid2: coarse [0,256) || scan [256,516) --------------------
__global__ __launch_bounds__(256) void mid2_kernel(const unsigned short* __restrict__ SQB,
    const unsigned short* __restrict__ MCT, const float* __restrict__ RELC,
    const float* __restrict__ ST,
    unsigned short* __restrict__ COB, unsigned short* __restrict__ STB)
{
  __shared__ __align__(16) char smem[27648];
  int b = blockIdx.x, tid = threadIdx.x;
  if (b < 256) {
    int h = b >> 4, st = b & 15;
    int w = tid >> 6, lane = tid & 63, lr = lane & 15, lg = lane >> 4;
    int s0 = st * 128;
    unsigned short* A_lds = (unsigned short*)smem;
    unsigned short* B_lds = (unsigned short*)(smem + 18432);
#pragma unroll
    for (int p = 0; p < 4; ++p) {
      int c = p * 256 + tid;
      int row = c >> 3, k8 = c & 7;
      *reinterpret_cast<u16x8*>(&A_lds[row * LDK + k8 * 8]) =
          *reinterpret_cast<const u16x8*>(SQB + (s0 + row) * 1024 + h * 64 + k8 * 8);
    }
#pragma unroll
    for (int p = 0; p < 2; ++p) {
      int c = p * 256 + tid;
      int e = c >> 3, k8 = c & 7;
      *reinterpret_cast<u16x8*>(&B_lds[e * LDK + k8 * 8]) =
          *reinterpret_cast<const u16x8*>(MCT + h * 4096 + e * 64 + k8 * 8);
    }
    __syncthreads();

    f32x4 acc[2][4];
#pragma unroll
    for (int m = 0; m < 2; ++m)
#pragma unroll
      for (int n = 0; n < 4; ++n)
#pragma unroll
        for (int r = 0; r < 4; ++r) acc[m][n][r] = 0.f;

#pragma unroll
    for (int kk = 0; kk < 2; ++kk) {
      bf16x8 af[2], bfr[4];
#pragma unroll
      for (int m = 0; m < 2; ++m)
        af[m] = *reinterpret_cast<const bf16x8*>(&A_lds[(w * 32 + m * 16 + lr) * LDK + kk * 32 + lg * 8]);
#pragma unroll
      for (int n = 0; n < 4; ++n)
        bfr[n] = *reinterpret_cast<const bf16x8*>(&B_lds[(n * 16 + lr) * LDK + kk * 32 + lg * 8]);
#pragma unroll
      for (int m = 0; m < 2; ++m)
#pragma unroll
        for (int n = 0; n < 4; ++n)
          acc[m][n] = __builtin_amdgcn_mfma_f32_16x16x32_bf16(af[m], bfr[n], acc[m][n], 0, 0, 0);
    }
#pragma unroll
    for (int m = 0; m < 2; ++m)
#pragma unroll
      for (int r = 0; r < 4; ++r) {
        int s = s0 + w * 32 + m * 16 + lg * 4 + r;
        float rc = fmaxf(RELC[h * 2048 + s], EPSF);
#pragma unroll
        for (int n = 0; n < 4; ++n)
          COB[s * 1024 + h * 64 + n * 16 + lr] = f2bf(acc[m][n][r] / rc);
      }
  } else {
    int gidx = (b - 256) * 256 + tid;
    int h = gidx / 4160, idx = gidx - h * 4160;
    if (h >= 16) return;
    float run = 0.f;
#pragma unroll 4
    for (int c = 0; c < 32; ++c) {
      float t = ST[(h * 32 + c) * 4160 + idx];
      STB[(h * 32 + c) * 4160 + idx] = f2bf(run);
      run += t;
    }
  }
}

// ---------------- mid3: lattn [0,512) || eg stage-1 mm [512,544) ------------
__global__ __launch_bounds__(256) void mid3_kernel(const unsigned short* __restrict__ SQB,
    const unsigned short* __restrict__ SKB, const unsigned short* __restrict__ VVB,
    const unsigned short* __restrict__ STB, const unsigned short* __restrict__ COB,
    const unsigned short* __restrict__ W1T,
    unsigned short* __restrict__ LOB, float* __restrict__ H1)
{
  __shared__ __align__(16) char smem[50688];
  int b = blockIdx.x, tid = threadIdx.x;
  if (b < 512) {
    int h = b >> 5, c = b & 31;
    int w = tid >> 6, lane = tid & 63, lr = lane & 15, lg = lane >> 4;
    int sb = c * 64;
    const unsigned short* stb = STB + (h * 32 + c) * 4160;
    unsigned short* A_lds = (unsigned short*)smem;
    unsigned short* K_lds = (unsigned short*)(smem + 9216);
    unsigned short* P_lds = (unsigned short*)(smem + 18432);
    unsigned short* V_lds = (unsigned short*)(smem + 29952);
    unsigned short* S_lds = (unsigned short*)(smem + 41472);

#pragma unroll
    for (int p = 0; p < 2; ++p) {
      int cc = p * 256 + tid;
      int row = cc >> 3, k8 = cc & 7;
      *reinterpret_cast<u16x8*>(&A_lds[row * LDK + k8 * 8]) =
          *reinterpret_cast<const u16x8*>(SQB + (sb + row) * 1024 + h * 64 + k8 * 8);
      *reinterpret_cast<u16x8*>(&K_lds[row * LDK + k8 * 8]) =
          *reinterpret_cast<const u16x8*>(SKB + (sb + row) * 1024 + h * 64 + k8 * 8);
    }
    for (int i = tid; i < 4096; i += 256) {
      int d = i >> 6, e = i & 63;
      P_lds[e * LDK + d] = stb[i];
    }
#pragma unroll
    for (int p = 0; p < 2; ++p) {
      int cc = p * 256 + tid;
      int t = cc >> 3, e8 = cc & 7;
      u16x8 v = *reinterpret_cast<const u16x8*>(VVB + (sb + t) * 1024 + h * 64 + e8 * 8);
#pragma unroll
      for (int j = 0; j < 8; ++j) V_lds[(e8 * 8 + j) * LDK + t] = (unsigned short)v[j];
    }
    if (tid < 64) {
      P_lds[64 * LDK + tid] = stb[4096 + tid];
      V_lds[64 * LDK + tid] = 0x3F80;
    }
    for (int i = tid; i < 15 * 64; i += 256) {
      int row = 65 + (i >> 6), col = i & 63;
      P_lds[row * LDK + col] = 0;
      V_lds[row * LDK + col] = 0;
    }
    __syncthreads();

    f32x4 acc_i[5];
#pragma unroll
    for (int n = 0; n < 5; ++n)
#pragma unroll
      for (int r = 0; r < 4; ++r) acc_i[n][r] = 0.f;
#pragma unroll
    for (int kk = 0; kk < 2; ++kk) {
      bf16x8 af = *reinterpret_cast<const bf16x8*>(&A_lds[(w * 16 + lr) * LDK + kk * 32 + lg * 8]);
#pragma unroll
      for (int n = 0; n < 5; ++n) {
        bf16x8 bfr = *reinterpret_cast<const bf16x8*>(&P_lds[(n * 16 + lr) * LDK + kk * 32 + lg * 8]);
        acc_i[n] = __builtin_amdgcn_mfma_f32_16x16x32_bf16(af, bfr, acc_i[n], 0, 0, 0);
      }
    }
    f32x4 acc_s[4];
#pragma unroll
    for (int n = 0; n < 4; ++n)
#pragma unroll
      for (int r = 0; r < 4; ++r) acc_s[n][r] = 0.f;
#pragma unroll
    for (int kk = 0; kk < 2; ++kk) {
      bf16x8 af = *reinterpret_cast<const bf16x8*>(&A_lds[(w * 16 + lr) * LDK + kk * 32 + lg * 8]);
#pragma unroll
      for (int n = 0; n < 4; ++n) {
        bf16x8 bfr = *reinterpret_cast<const bf16x8*>(&K_lds[(n * 16 + lr) * LDK + kk * 32 + lg * 8]);
        acc_s[n] = __builtin_amdgcn_mfma_f32_16x16x32_bf16(af, bfr, acc_s[n], 0, 0, 0);
      }
    }
#pragma unroll
    for (int n = 0; n < 4; ++n)
#pragma unroll
      for (int r = 0; r < 4; ++r) {
        int s_loc = w * 16 + lg * 4 + r, t = n * 16 + lr;
        float v = (t <= s_loc) ? acc_s[n][r] : 0.f;
        S_lds[s_loc * LDK + t] = f2bf(v);
      }
    __syncthreads();
    f32x4 acc_p[5];
#pragma unroll
    for (int n = 0; n < 5; ++n)
#pragma unroll
      for (int r = 0; r < 4; ++r) acc_p[n][r] = 0.f;
#pragma unroll
    for (int kk = 0; kk < 2; ++kk) {
      bf16x8 af = *reinterpret_cast<const bf16x8*>(&S_lds[(w * 16 + lr) * LDK + kk * 32 + lg * 8]);
#pragma unroll
      for (int n = 0; n < 5; ++n) {
        bf16x8 bfr = *reinterpret_cast<const bf16x8*>(&V_lds[(n * 16 + lr) * LDK + kk * 32 + lg * 8]);
        acc_p[n] = __builtin_amdgcn_mfma_f32_16x16x32_bf16(af, bfr, acc_p[n], 0, 0, 0);
      }
    }
#pragma unroll
    for (int r = 0; r < 4; ++r) {
      float den = acc_i[4][r] + acc_p[4][r];
      den = __shfl(den, lane & 48);
      den = fmaxf(den, EPSF);
      int s = sb + w * 16 + lg * 4 + r;
#pragma unroll
      for (int n = 0; n < 4; ++n)
        LOB[s * 1024 + h * 64 + n * 16 + lr] = f2bf((acc_i[n][r] + acc_p[n][r]) / den);
    }
  } else {
    int bb = b - 512;
    int m0 = (bb >> 1) * 128, n0 = (bb & 1) * 128;
    int wid = tid >> 6, lane = tid & 63;
    int wr = wid >> 1, wc = wid & 1;
    int lr = lane & 15, lg = lane >> 4;
    unsigned short* As = (unsigned short*)smem;
    unsigned short* Bs = (unsigned short*)(smem + 18432);

    f32x4 acc[4][4];
#pragma unroll
    for (int m = 0; m < 4; ++m)
#pragma unroll
      for (int n = 0; n < 4; ++n)
#pragma unroll
        for (int r = 0; r < 4; ++r) acc[m][n][r] = 0.f;

    for (int kt = 0; kt < 16; ++kt) {
      int k0 = kt * 64;
#pragma unroll
      for (int p = 0; p < 4; ++p) {
        int c = p * 256 + tid;
        int row = c >> 3, k8 = c & 7;
        u16x8 va = *reinterpret_cast<const u16x8*>(COB + (m0 + row) * 1024 + k0 + k8 * 8);
        *reinterpret_cast<u16x8*>(&As[row * LDK + k8 * 8]) = va;
        u16x8 vb = *reinterpret_cast<const u16x8*>(W1T + (n0 + row) * 1024 + k0 + k8 * 8);
        *reinterpret_cast<u16x8*>(&Bs[row * LDK + k8 * 8]) = vb;
      }
      __syncthreads();
#pragma unroll
      for (int kk = 0; kk < 2; ++kk) {
        bf16x8 af[4], bfr[4];
#pragma unroll
        for (int m = 0; m < 4; ++m)
          af[m] = *reinterpret_cast<const bf16x8*>(&As[(wr * 64 + m * 16 + lr) * LDK + kk * 32 + lg * 8]);
#pragma unroll
        for (int n = 0; n < 4; ++n)
          bfr[n] = *reinterpret_cast<const bf16x8*>(&Bs[(wc * 64 + n * 16 + lr) * LDK + kk * 32 + lg * 8]);
#pragma unroll
        for (int m = 0; m < 4; ++m)
#pragma unroll
          for (int n = 0; n < 4; ++n)
            acc[m][n] = __builtin_amdgcn_mfma_f32_16x16x32_bf16(af[m], bfr[n], acc[m][n], 0, 0, 0);
      }
      __syncthreads();
    }
#pragma unroll
    for (int m = 0; m < 4; ++m)
#pragma unroll
      for (int n = 0; n < 4; ++n)
#pragma unroll
        for (int r = 0; r < 4; ++r)
          H1[(m0 + wr * 64 + m * 16 + lg * 4 + r) * 256 + n0 + wc * 64 + n * 16 + lr] = acc[m][n][r];
  }
}

// ---------------- fine retrieval + combine + fused eg_fin, bf16 MFMA --------
__global__ __launch_bounds__(256) void fine_mfma(const unsigned short* __restrict__ SQB,
    const unsigned short* __restrict__ FMT, const float* __restrict__ RELS,
    const float* __restrict__ PARTS, const float* __restrict__ H1,
    const float* __restrict__ B1, const float* __restrict__ W2,
    const float* __restrict__ B2,
    const unsigned short* __restrict__ COB, unsigned short* __restrict__ MOB)
{
  int h = blockIdx.x, st = blockIdx.y;
  int tid = threadIdx.x;
  int w = tid >> 6, lane = tid & 63;
  int lr = lane & 15, lg = lane >> 4;
  int s0 = st * 128;

  __shared__ unsigned short A_lds[128 * LDK];
  __shared__ unsigned short B_lds[4 * 64 * LDK];
  __shared__ float rmean[4];
  __shared__ float epb[128];
  if (tid < 4) {
    float s = 0.f;
    for (int t = 0; t < 32; ++t) s += PARTS[tid * 512 + h * 32 + t];
    rmean[tid] = s * (1.f / 2048.f);
  }
  // fused eg_fin: EP for this block's 128 rows (thread pair per row)
  {
    int row = tid >> 1, half = tid & 1;
    const float* hrow = H1 + (s0 + row) * 256 + half * 128;
    const float* b1p = B1 + half * 128;
    const float* w2p = W2 + half * 128;
    float ae = 0.f;
#pragma unroll 8
    for (int j = 0; j < 32; ++j) {
      float4 hv = *reinterpret_cast<const float4*>(hrow + j * 4);
      float4 bv = *reinterpret_cast<const float4*>(b1p + j * 4);
      float4 wv = *reinterpret_cast<const float4*>(w2p + j * 4);
      ae += fmaxf(hv.x + bv.x, 0.f) * wv.x + fmaxf(hv.y + bv.y, 0.f) * wv.y
          + fmaxf(hv.z + bv.z, 0.f) * wv.z + fmaxf(hv.w + bv.w, 0.f) * wv.w;
    }
    ae += __shfl_xor(ae, 1, 64);
    if (half == 0) epb[row] = 1.f / (1.f + expf(-(ae + B2[0])));
  }

#pragma unroll
  for (int p = 0; p < 4; ++p) {
    int c = p * 256 + tid;
    int row = c >> 3, k8 = c & 7;
    *reinterpret_cast<u16x8*>(&A_lds[row * LDK + k8 * 8]) =
        *reinterpret_cast<const u16x8*>(SQB + (s0 + row) * 1024 + h * 64 + k8 * 8);
  }
#pragma unroll
  for (int p = 0; p < 8; ++p) {
    int c = p * 256 + tid;
    int f = c >> 9, rem = c & 511;
    int e = rem >> 3, k8 = rem & 7;
    *reinterpret_cast<u16x8*>(&B_lds[(f * 64 + e) * LDK + k8 * 8]) =
        *reinterpret_cast<const u16x8*>(FMT + (f * 16 + h) * 4096 + e * 64 + k8 * 8);
  }
  __syncthreads();

  f32x4 acc[4][2][4];
#pragma unroll
  for (int f = 0; f < 4; ++f)
#pragma unroll
    for (int m = 0; m < 2; ++m)
#pragma unroll
      for (int n = 0; n < 4; ++n)
#pragma unroll
        for (int r = 0; r < 4; ++r) acc[f][m][n][r] = 0.f;

#pragma unroll
  for (int kk = 0; kk < 2; ++kk) {
    bf16x8 af[2];
#pragma unroll
    for (int m = 0; m < 2; ++m)
      af[m] = *reinterpret_cast<const bf16x8*>(&A_lds[(w * 32 + m * 16 + lr) * LDK + kk * 32 + lg * 8]);
#pragma unroll
    for (int f = 0; f < 4; ++f) {
      bf16x8 bf4[4];
#pragma unroll
      for (int n = 0; n < 4; ++n)
        bf4[n] = *reinterpret_cast<const bf16x8*>(&B_lds[(f * 64 + n * 16 + lr) * LDK + kk * 32 + lg * 8]);
#pragma unroll
      for (int m = 0; m < 2; ++m)
#pragma unroll
        for (int n = 0; n < 4; ++n)
          acc[f][m][n] = __builtin_amdgcn_mfma_f32_16x16x32_bf16(af[m], bf4[n], acc[f][m][n], 0, 0, 0);
    }
  }

  float rm = fmaxf(fmaxf(rmean[0], rmean[1]), fmaxf(rmean[2], rmean[3]));
  float e0 = expf(rmean[0] - rm), e1 = expf(rmean[1] - rm);
  float e2 = expf(rmean[2] - rm), e3 = expf(rmean[3] - rm);
  float winv = 1.f / (e0 + e1 + e2 + e3);
  float w0 = e0 * winv, w1 = e1 * winv, w2 = e2 * winv, w3 = e3 * winv;

#pragma unroll
  for (int m = 0; m < 2; ++m)
#pragma unroll
    for (int r = 0; r < 4; ++r) {
      int s = s0 + w * 32 + m * 16 + lg * 4 + r;
      float e = epb[s - s0];
      float i0 = w0 / fmaxf(RELS[0 * 32768 + h * 2048 + s], EPSF);
      float i1 = w1 / fmaxf(RELS[1 * 32768 + h * 2048 + s], EPSF);
      float i2 = w2 / fmaxf(RELS[2 * 32768 + h * 2048 + s], EPSF);
      float i3 = w3 / fmaxf(RELS[3 * 32768 + h * 2048 + s], EPSF);
#pragma unroll
      for (int n = 0; n < 4; ++n) {
        int dg = h * 64 + n * 16 + lr;
        float fine = acc[0][m][n][r] * i0 + acc[1][m][n][r] * i1
                   + acc[2][m][n][r] * i2 + acc[3][m][n][r] * i3;
        float cv = bf2f(COB[s * 1024 + dg]);
        MOB[s * 1024 + dg] = f2bf(e * fine + (1.f - e) * cv);
      }
    }
}

// final out-proj: A = gate-combined(mob, lob) computed during staging
__global__ __launch_bounds__(256) void mm_gate_bf16(const unsigned short* __restrict__ MOB,
    const unsigned short* __restrict__ LOB, const float* __restrict__ MG,
    const unsigned short* __restrict__ BT, float* __restrict__ C)
{
  __shared__ unsigned short As[128 * LDK];
  __shared__ unsigned short Bs[128 * LDK];
  __shared__ float gs[16];
  int tid = threadIdx.x;
  int m0 = blockIdx.y * 128, n0 = blockIdx.x * 128;
  int wid = tid >> 6, lane = tid & 63;
  int wr = wid >> 1, wc = wid & 1;
  int lr = lane & 15, lg = lane >> 4;
  if (tid < 16) gs[tid] = 1.f / (1.f + expf(-MG[tid]));
  __syncthreads();

  f32x4 acc[4][4];
#pragma unroll
  for (int m = 0; m < 4; ++m)
#pragma unroll
    for (int n = 0; n < 4; ++n)
#pragma unroll
      for (int r = 0; r < 4; ++r) acc[m][n][r] = 0.f;

  for (int kt = 0; kt < 16; ++kt) {
    int k0 = kt * 64;
#pragma unroll
    for (int p = 0; p < 4; ++p) {
      int c = p * 256 + tid;
      int row = c >> 3, k8 = c & 7;
      int col = k0 + k8 * 8;
      float g = gs[col >> 6];
      u16x8 mv = *reinterpret_cast<const u16x8*>(MOB + (m0 + row) * 1024 + col);
      u16x8 lv = *reinterpret_cast<const u16x8*>(LOB + (m0 + row) * 1024 + col);
      u16x8 o;
#pragma unroll
      for (int j = 0; j < 8; ++j)
        o[j] = f2bf(g * bf2f((unsigned short)mv[j]) + (1.f - g) * bf2f((unsigned short)lv[j]));
      *reinterpret_cast<u16x8*>(&As[row * LDK + k8 * 8]) = o;
      u16x8 vb = *reinterpret_cast<const u16x8*>(BT + (n0 + row) * 1024 + k0 + k8 * 8);
      *reinterpret_cast<u16x8*>(&Bs[row * LDK + k8 * 8]) = vb;
    }
    __syncthreads();
#pragma unroll
    for (int kk = 0; kk < 2; ++kk) {
      bf16x8 af[4], bfr[4];
#pragma unroll
      for (int m = 0; m < 4; ++m)
        af[m] = *reinterpret_cast<const bf16x8*>(&As[(wr * 64 + m * 16 + lr) * LDK + kk * 32 + lg * 8]);
#pragma unroll
      for (int n = 0; n < 4; ++n)
        bfr[n] = *reinterpret_cast<const bf16x8*>(&Bs[(wc * 64 + n * 16 + lr) * LDK + kk * 32 + lg * 8]);
#pragma unroll
      for (int m = 0; m < 4; ++m)
#pragma unroll
        for (int n = 0; n < 4; ++n)
          acc[m][n] = __builtin_amdgcn_mfma_f32_16x16x32_bf16(af[m], bfr[n], acc[m][n], 0, 0, 0);
    }
    __syncthreads();
  }
#pragma unroll
  for (int m = 0; m < 4; ++m)
#pragma unroll
    for (int n = 0; n < 4; ++n)
#pragma unroll
      for (int r = 0; r < 4; ++r)
        C[(m0 + wr * 64 + m * 16 + lg * 4 + r) * 1024 + n0 + wc * 64 + n * 16 + lr] = acc[m][n][r];
}

// ---------------------------------------------------------------------------
extern "C" void kernel_launch(void* const* d_in, const int* in_sizes, int n_in,
                              void* d_out, int out_size, void* d_ws, size_t ws_size,
                              hipStream_t stream)
{
  const float* hs   = (const float*)d_in[0];
  const float* wq   = (const float*)d_in[1];
  const float* wk   = (const float*)d_in[2];
  const float* wv   = (const float*)d_in[3];
  const float* wo   = (const float*)d_in[4];
  const float* mg   = (const float*)d_in[5];
  const float* egw1 = (const float*)d_in[6];
  const float* egb1 = (const float*)d_in[7];
  const float* egw2 = (const float*)d_in[8];
  const float* egb2 = (const float*)d_in[9];
  const float* fm   = (const float*)d_in[10];
  const float* fn   = (const float*)d_in[11];
  float* out = (float*)d_out;

  // ---- disjoint workspace layout ----
  float* ws     = (float*)d_ws;
  float* zc     = ws;                       // 1024
  float* rels   = zc + 1024;                // 131072
  float* parts  = rels + 131072;            // 2048
  float* relc   = parts + 2048;             // 32768
  float* states = relc + 32768;             // 2129920
  float* h1     = states + 2129920;         // 524288
  unsigned short* hsb  = (unsigned short*)(h1 + 524288);   // 2097152 each
  unsigned short* sqb  = hsb + 2097152;
  unsigned short* skb  = sqb + 2097152;
  unsigned short* vvb  = skb + 2097152;
  unsigned short* cob  = vvb + 2097152;
  unsigned short* mob  = cob + 2097152;
  unsigned short* lob  = mob + 2097152;
  unsigned short* wqT  = lob + 2097152;     // 1048576 each
  unsigned short* wkT  = wqT + 1048576;
  unsigned short* wvT  = wkT + 1048576;
  unsigned short* woT  = wvT + 1048576;
  unsigned short* w1T  = woT + 1048576;     // 262144
  unsigned short* fmbT = w1T + 262144;      // 262144
  unsigned short* mcT  = fmbT + 262144;     // 65536
  unsigned short* statesb = mcT + 65536;    // 2129920

  prep_kernel<<<3264, 256, 0, stream>>>(fm, fn, hs, wq, wk, wv, wo, egw1,
      mcT, zc, wqT, wkT, wvT, woT, w1T, fmbT, hsb);
  proj_bf16<<<dim3(8, 16, 3), 256, 0, stream>>>(hsb, wqT, wkT, wvT, sqb, skb, vvb);
  mid1_kernel<<<1024, 256, 0, stream>>>(sqb, zc, fn, skb, vvb, relc, rels, parts, states);
  mid2_kernel<<<516, 256, 0, stream>>>(sqb, mcT, relc, states, cob, statesb);
  mid3_kernel<<<544, 256, 0, stream>>>(sqb, skb, vvb, statesb, cob, w1T, lob, h1);
  fine_mfma<<<dim3(16, 16), 256, 0, stream>>>(sqb, fmbT, rels, parts, h1,
      egb1, egw2, egb2, cob, mob);
  mm_gate_bf16<<<dim3(8, 16), 256, 0, stream>>>(mob, lob, mg, woT, out);
}

// Round 23
// 119.559 us; speedup vs baseline: 1.0390x; 1.0390x over previous
//
#include <hip/hip_runtime.h>
#include <cmath>

#define EPSF 1e-6f
#define LDK 72   // padded stride: conflict-free ds_read_b128 fragments

// ---------------------------------------------------------------------------
// Shapes: B=1, S=2048, H=16, D=64, hid=1024
// FINAL = R19 structure (119.7us measured): 8 launches, all-MFMA bf16,
// merged independent kernels (rels||chunk, coarse||scan, lattn||eg1),
// mega-prep, gate fused into out-GEMM.
// R20/R22's eg_fin-into-fine fusion regressed (124.2us) -> reverted.
// ---------------------------------------------------------------------------

typedef __attribute__((ext_vector_type(8))) short bf16x8;
typedef __attribute__((ext_vector_type(4))) float f32x4;
typedef __attribute__((ext_vector_type(8))) unsigned short u16x8;

__device__ __forceinline__ float wave_allsum(float v) {
#pragma unroll
  for (int off = 32; off > 0; off >>= 1) v += __shfl_xor(v, off, 64);
  return v;
}

__device__ __forceinline__ unsigned short f2bf(float f) {  // RNE f32->bf16
  unsigned int u = __float_as_uint(f);
  unsigned int r = (u + 0x7fffu + ((u >> 16) & 1u)) >> 16;
  return (unsigned short)r;
}
__device__ __forceinline__ float bf2f(unsigned short u) {
  return __uint_as_float(((unsigned int)u) << 16);
}

// ---------------- mega-prep: all input casts in one launch ------------------
__global__ __launch_bounds__(256) void prep_kernel(const float* __restrict__ FM,
    const float* __restrict__ FN, const float* __restrict__ HS,
    const float* __restrict__ W0, const float* __restrict__ W1,
    const float* __restrict__ W2, const float* __restrict__ W3,
    const float* __restrict__ EGW1,
    unsigned short* __restrict__ MCT, float* __restrict__ ZC,
    unsigned short* __restrict__ T0, unsigned short* __restrict__ T1,
    unsigned short* __restrict__ T2, unsigned short* __restrict__ T3,
    unsigned short* __restrict__ W1T, unsigned short* __restrict__ FMT,
    unsigned short* __restrict__ HSB)
{
  int b = blockIdx.x, tid = threadIdx.x;
  __shared__ float tile[64][65];
  if (b < 64) {
    int h = b >> 2, q = b & 3;
    for (int i = tid; i < 1024; i += 256) {
      int dpl = i >> 6, e = i & 63;
      int idx = (q * 16 + dpl) * 64 + e;
      tile[dpl][e] = FM[(0 * 16 + h) * 4096 + idx] + FM[(1 * 16 + h) * 4096 + idx]
                   + FM[(2 * 16 + h) * 4096 + idx] + FM[(3 * 16 + h) * 4096 + idx];
    }
    if (q == 0 && tid < 64)
      ZC[h * 64 + tid] = FN[h * 64 + tid] + FN[1024 + h * 64 + tid]
                       + FN[2048 + h * 64 + tid] + FN[3072 + h * 64 + tid];
    __syncthreads();
    for (int i = tid; i < 1024; i += 256) {
      int e = i >> 4, dpl = i & 15;
      MCT[h * 4096 + e * 64 + q * 16 + dpl] = f2bf(tile[dpl][e]);
    }
  } else if (b < 1088) {
    int r0 = b - 64, z = r0 >> 8, rem = r0 & 255;
    const float* W = (z == 0) ? W0 : (z == 1) ? W1 : (z == 2) ? W2 : W3;
    unsigned short* WT = (z == 0) ? T0 : (z == 1) ? T1 : (z == 2) ? T2 : T3;
    int n0 = (rem & 15) * 64, k0 = (rem >> 4) * 64;
    for (int i = tid; i < 4096; i += 256) {
      int r = i >> 6, c = i & 63;
      tile[r][c] = W[(k0 + r) * 1024 + n0 + c];
    }
    __syncthreads();
    for (int i = tid; i < 1024; i += 256) {
      int r = i >> 4, c4 = (i & 15) * 4;
      ushort4 o;
      o.x = f2bf(tile[c4 + 0][r]); o.y = f2bf(tile[c4 + 1][r]);
      o.z = f2bf(tile[c4 + 2][r]); o.w = f2bf(tile[c4 + 3][r]);
      *reinterpret_cast<ushort4*>(&WT[(n0 + r) * 1024 + k0 + c4]) = o;
    }
  } else if (b < 1152) {
    int rem = b - 1088;
    int n0 = (rem & 3) * 64, k0 = (rem >> 2) * 64;
    for (int i = tid; i < 4096; i += 256) {
      int r = i >> 6, c = i & 63;
      tile[r][c] = EGW1[(k0 + r) * 256 + n0 + c];
    }
    __syncthreads();
    for (int i = tid; i < 1024; i += 256) {
      int r = i >> 4, c4 = (i & 15) * 4;
      ushort4 o;
      o.x = f2bf(tile[c4 + 0][r]); o.y = f2bf(tile[c4 + 1][r]);
      o.z = f2bf(tile[c4 + 2][r]); o.w = f2bf(tile[c4 + 3][r]);
      *reinterpret_cast<ushort4*>(&W1T[(n0 + r) * 1024 + k0 + c4]) = o;
    }
  } else if (b < 1216) {
    int mat = b - 1152;
    const float* src = FM + mat * 4096;
    for (int i = tid; i < 4096; i += 256) tile[i >> 6][i & 63] = src[i];
    __syncthreads();
    unsigned short* dst = FMT + mat * 4096;
    for (int i = tid; i < 4096; i += 256) {
      int e = i >> 6, dp = i & 63;
      dst[e * 64 + dp] = f2bf(tile[dp][e]);
    }
  } else {
    int i = (b - 1216) * 256 + tid;
    float4 v = *reinterpret_cast<const float4*>(HS + i * 4);
    ushort4 o; o.x = f2bf(v.x); o.y = f2bf(v.y); o.z = f2bf(v.z); o.w = f2bf(v.w);
    *reinterpret_cast<ushort4*>(HSB + i * 4) = o;
  }
}

// fused QKV projections -> bf16
__global__ __launch_bounds__(256) void proj_bf16(const unsigned short* __restrict__ A,
    const unsigned short* __restrict__ WqT, const unsigned short* __restrict__ WkT,
    const unsigned short* __restrict__ WvT,
    unsigned short* __restrict__ Oq, unsigned short* __restrict__ Ok,
    unsigned short* __restrict__ Ov)
{
  int z = blockIdx.z;
  const unsigned short* BT = (z == 0) ? WqT : (z == 1) ? WkT : WvT;
  unsigned short* C = (z == 0) ? Oq : (z == 1) ? Ok : Ov;

  __shared__ unsigned short As[128 * LDK];
  __shared__ unsigned short Bs[128 * LDK];
  int tid = threadIdx.x;
  int m0 = blockIdx.y * 128, n0 = blockIdx.x * 128;
  int wid = tid >> 6, lane = tid & 63;
  int wr = wid >> 1, wc = wid & 1;
  int lr = lane & 15, lg = lane >> 4;
  int act = (z < 2) ? 1 : 0;

  f32x4 acc[4][4];
#pragma unroll
  for (int m = 0; m < 4; ++m)
#pragma unroll
    for (int n = 0; n < 4; ++n)
#pragma unroll
      for (int r = 0; r < 4; ++r) acc[m][n][r] = 0.f;

  for (int kt = 0; kt < 16; ++kt) {
    int k0 = kt * 64;
#pragma unroll
    for (int p = 0; p < 4; ++p) {
      int c = p * 256 + tid;
      int row = c >> 3, k8 = c & 7;
      u16x8 va = *reinterpret_cast<const u16x8*>(A + (m0 + row) * 1024 + k0 + k8 * 8);
      *reinterpret_cast<u16x8*>(&As[row * LDK + k8 * 8]) = va;
      u16x8 vb = *reinterpret_cast<const u16x8*>(BT + (n0 + row) * 1024 + k0 + k8 * 8);
      *reinterpret_cast<u16x8*>(&Bs[row * LDK + k8 * 8]) = vb;
    }
    __syncthreads();
#pragma unroll
    for (int kk = 0; kk < 2; ++kk) {
      bf16x8 af[4], bfr[4];
#pragma unroll
      for (int m = 0; m < 4; ++m)
        af[m] = *reinterpret_cast<const bf16x8*>(&As[(wr * 64 + m * 16 + lr) * LDK + kk * 32 + lg * 8]);
#pragma unroll
      for (int n = 0; n < 4; ++n)
        bfr[n] = *reinterpret_cast<const bf16x8*>(&Bs[(wc * 64 + n * 16 + lr) * LDK + kk * 32 + lg * 8]);
#pragma unroll
      for (int m = 0; m < 4; ++m)
#pragma unroll
        for (int n = 0; n < 4; ++n)
          acc[m][n] = __builtin_amdgcn_mfma_f32_16x16x32_bf16(af[m], bfr[n], acc[m][n], 0, 0, 0);
    }
    __syncthreads();
  }
#pragma unroll
  for (int m = 0; m < 4; ++m)
#pragma unroll
    for (int n = 0; n < 4; ++n)
#pragma unroll
      for (int r = 0; r < 4; ++r) {
        float v = acc[m][n][r];
        if (act) v = v > 0.f ? v + 1.f : expf(v);
        C[(m0 + wr * 64 + m * 16 + lg * 4 + r) * 1024 + n0 + wc * 64 + n * 16 + lr] = f2bf(v);
      }
}

// ---------------- mid1: rels [0,512) || chunk_mfma [512,1024) ---------------
__global__ __launch_bounds__(256) void mid1_kernel(const unsigned short* __restrict__ SQB,
    const float* __restrict__ ZC, const float* __restrict__ FN,
    const unsigned short* __restrict__ SKB, const unsigned short* __restrict__ VVB,
    float* __restrict__ RELC, float* __restrict__ RELS, float* __restrict__ PARTS,
    float* __restrict__ ST)
{
  __shared__ __align__(16) char smem[20736];
  int b = blockIdx.x, tid = threadIdx.x;
  if (b < 512) {
    int h = b >> 5, st = b & 31;
    int s0 = st * 64;
    float (*sqT)[68] = (float(*)[68])smem;
    float (*zf)[64]  = (float(*)[64])(smem + 17408);
    float (*relb)[64]= (float(*)[64])(smem + 18688);
#pragma unroll
    for (int p = 0; p < 2; ++p) {
      int cidx = p * 256 + tid;
      int r = cidx >> 3, d8 = cidx & 7;
      u16x8 v = *reinterpret_cast<const u16x8*>(SQB + (s0 + r) * 1024 + h * 64 + d8 * 8);
#pragma unroll
      for (int j = 0; j < 8; ++j) sqT[d8 * 8 + j][r] = bf2f((unsigned short)v[j]);
    }
    for (int idx = tid; idx < 320; idx += 256) {
      int w = idx >> 6, d = idx & 63;
      zf[w][d] = (w == 0) ? ZC[h * 64 + d] : FN[(w - 1) * 1024 + h * 64 + d];
    }
    __syncthreads();
    {
      int s = tid & 63, wh = tid >> 6;
      float r = 0.f;
      for (int dp = 0; dp < 64; ++dp) r += sqT[dp][s] * zf[wh][dp];
      relb[wh][s] = r;
      if (wh == 0) {
        float r4 = 0.f;
        for (int dp = 0; dp < 64; ++dp) r4 += sqT[dp][s] * zf[4][dp];
        relb[4][s] = r4;
      }
    }
    __syncthreads();
    if (tid < 64) {
      RELC[h * 2048 + s0 + tid] = relb[0][tid];
#pragma unroll
      for (int f = 0; f < 4; ++f)
        RELS[f * 32768 + h * 2048 + s0 + tid] = relb[1 + f][tid];
#pragma unroll
      for (int f = 0; f < 4; ++f) {
        float v = wave_allsum(relb[1 + f][tid]);
        if (tid == 0) PARTS[f * 512 + h * 32 + st] = v;
      }
    }
  } else {
    int bb = b - 512;
    int h = bb >> 5, c = bb & 31;
    int w = tid >> 6, lane = tid & 63, lr = lane & 15, lg = lane >> 4;
    int sb = c * 64;
    unsigned short* A_lds = (unsigned short*)smem;
    unsigned short* B_lds = (unsigned short*)(smem + 9216);
#pragma unroll
    for (int p = 0; p < 2; ++p) {
      int cc = p * 256 + tid;
      int t = cc >> 3, e8 = cc & 7;
      u16x8 kv = *reinterpret_cast<const u16x8*>(SKB + (sb + t) * 1024 + h * 64 + e8 * 8);
      u16x8 vv = *reinterpret_cast<const u16x8*>(VVB + (sb + t) * 1024 + h * 64 + e8 * 8);
#pragma unroll
      for (int j = 0; j < 8; ++j) {
        A_lds[(e8 * 8 + j) * LDK + t] = (unsigned short)kv[j];
        B_lds[(e8 * 8 + j) * LDK + t] = (unsigned short)vv[j];
      }
    }
    if (tid < 64) B_lds[64 * LDK + tid] = 0x3F80;
    for (int i = tid; i < 15 * 64; i += 256) {
      int row = 65 + (i >> 6), col = i & 63;
      B_lds[row * LDK + col] = 0;
    }
    __syncthreads();

    f32x4 acc[5];
#pragma unroll
    for (int n = 0; n < 5; ++n)
#pragma unroll
      for (int r = 0; r < 4; ++r) acc[n][r] = 0.f;
#pragma unroll
    for (int kk = 0; kk < 2; ++kk) {
      bf16x8 af = *reinterpret_cast<const bf16x8*>(&A_lds[(w * 16 + lr) * LDK + kk * 32 + lg * 8]);
#pragma unroll
      for (int n = 0; n < 5; ++n) {
        bf16x8 bfr = *reinterpret_cast<const bf16x8*>(&B_lds[(n * 16 + lr) * LDK + kk * 32 + lg * 8]);
        acc[n] = __builtin_amdgcn_mfma_f32_16x16x32_bf16(af, bfr, acc[n], 0, 0, 0);
      }
    }
    float* base = ST + (h * 32 + c) * 4160;
#pragma unroll
    for (int r = 0; r < 4; ++r) {
      int d = w * 16 + lg * 4 + r;
#pragma unroll
      for (int n = 0; n < 4; ++n)
        base[d * 64 + n * 16 + lr] = acc[n][r];
      if (lr == 0) base[4096 + d] = acc[4][r];
    }
  }
}

// ---------------- mid2: coarse [0,256) || scan [256,516) --------------------
__global__ __launch_bounds__(256) void mid2_kernel(const unsigned short* __restrict__ SQB,
    const unsigned short* __restrict__ MCT, const float* __restrict__ RELC,
    const float* __restrict__ ST,
    unsigned short* __restrict__ COB, unsigned short* __restrict__ STB)
{
  __shared__ __align__(16) char smem[27648];
  int b = blockIdx.x, tid = threadIdx.x;
  if (b < 256) {
    int h = b >> 4, st = b & 15;
    int w = tid >> 6, lane = tid & 63, lr = lane & 15, lg = lane >> 4;
    int s0 = st * 128;
    unsigned short* A_lds = (unsigned short*)smem;
    unsigned short* B_lds = (unsigned short*)(smem + 18432);
#pragma unroll
    for (int p = 0; p < 4; ++p) {
      int c = p * 256 + tid;
      int row = c >> 3, k8 = c & 7;
      *reinterpret_cast<u16x8*>(&A_lds[row * LDK + k8 * 8]) =
          *reinterpret_cast<const u16x8*>(SQB + (s0 + row) * 1024 + h * 64 + k8 * 8);
    }
#pragma unroll
    for (int p = 0; p < 2; ++p) {
      int c = p * 256 + tid;
      int e = c >> 3, k8 = c & 7;
      *reinterpret_cast<u16x8*>(&B_lds[e * LDK + k8 * 8]) =
          *reinterpret_cast<const u16x8*>(MCT + h * 4096 + e * 64 + k8 * 8);
    }
    __syncthreads();

    f32x4 acc[2][4];
#pragma unroll
    for (int m = 0; m < 2; ++m)
#pragma unroll
      for (int n = 0; n < 4; ++n)
#pragma unroll
        for (int r = 0; r < 4; ++r) acc[m][n][r] = 0.f;

#pragma unroll
    for (int kk = 0; kk < 2; ++kk) {
      bf16x8 af[2], bfr[4];
#pragma unroll
      for (int m = 0; m < 2; ++m)
        af[m] = *reinterpret_cast<const bf16x8*>(&A_lds[(w * 32 + m * 16 + lr) * LDK + kk * 32 + lg * 8]);
#pragma unroll
      for (int n = 0; n < 4; ++n)
        bfr[n] = *reinterpret_cast<const bf16x8*>(&B_lds[(n * 16 + lr) * LDK + kk * 32 + lg * 8]);
#pragma unroll
      for (int m = 0; m < 2; ++m)
#pragma unroll
        for (int n = 0; n < 4; ++n)
          acc[m][n] = __builtin_amdgcn_mfma_f32_16x16x32_bf16(af[m], bfr[n], acc[m][n], 0, 0, 0);
    }
#pragma unroll
    for (int m = 0; m < 2; ++m)
#pragma unroll
      for (int r = 0; r < 4; ++r) {
        int s = s0 + w * 32 + m * 16 + lg * 4 + r;
        float rc = fmaxf(RELC[h * 2048 + s], EPSF);
#pragma unroll
        for (int n = 0; n < 4; ++n)
          COB[s * 1024 + h * 64 + n * 16 + lr] = f2bf(acc[m][n][r] / rc);
      }
  } else {
    int gidx = (b - 256) * 256 + tid;
    int h = gidx / 4160, idx = gidx - h * 4160;
    if (h >= 16) return;
    float run = 0.f;
#pragma unroll 4
    for (int c = 0; c < 32; ++c) {
      float t = ST[(h * 32 + c) * 4160 + idx];
      STB[(h * 32 + c) * 4160 + idx] = f2bf(run);
      run += t;
    }
  }
}

// ---------------- mid3: lattn [0,512) || eg stage-1 mm [512,544) ------------
__global__ __launch_bounds__(256) void mid3_kernel(const unsigned short* __restrict__ SQB,
    const unsigned short* __restrict__ SKB, const unsigned short* __restrict__ VVB,
    const unsigned short* __restrict__ STB, const unsigned short* __restrict__ COB,
    const unsigned short* __restrict__ W1T,
    unsigned short* __restrict__ LOB, float* __restrict__ H1)
{
  __shared__ __align__(16) char smem[50688];
  int b = blockIdx.x, tid = threadIdx.x;
  if (b < 512) {
    int h = b >> 5, c = b & 31;
    int w = tid >> 6, lane = tid & 63, lr = lane & 15, lg = lane >> 4;
    int sb = c * 64;
    const unsigned short* stb = STB + (h * 32 + c) * 4160;
    unsigned short* A_lds = (unsigned short*)smem;
    unsigned short* K_lds = (unsigned short*)(smem + 9216);
    unsigned short* P_lds = (unsigned short*)(smem + 18432);
    unsigned short* V_lds = (unsigned short*)(smem + 29952);
    unsigned short* S_lds = (unsigned short*)(smem + 41472);

#pragma unroll
    for (int p = 0; p < 2; ++p) {
      int cc = p * 256 + tid;
      int row = cc >> 3, k8 = cc & 7;
      *reinterpret_cast<u16x8*>(&A_lds[row * LDK + k8 * 8]) =
          *reinterpret_cast<const u16x8*>(SQB + (sb + row) * 1024 + h * 64 + k8 * 8);
      *reinterpret_cast<u16x8*>(&K_lds[row * LDK + k8 * 8]) =
          *reinterpret_cast<const u16x8*>(SKB + (sb + row) * 1024 + h * 64 + k8 * 8);
    }
    for (int i = tid; i < 4096; i += 256) {
      int d = i >> 6, e = i & 63;
      P_lds[e * LDK + d] = stb[i];
    }
#pragma unroll
    for (int p = 0; p < 2; ++p) {
      int cc = p * 256 + tid;
      int t = cc >> 3, e8 = cc & 7;
      u16x8 v = *reinterpret_cast<const u16x8*>(VVB + (sb + t) * 1024 + h * 64 + e8 * 8);
#pragma unroll
      for (int j = 0; j < 8; ++j) V_lds[(e8 * 8 + j) * LDK + t] = (unsigned short)v[j];
    }
    if (tid < 64) {
      P_lds[64 * LDK + tid] = stb[4096 + tid];
      V_lds[64 * LDK + tid] = 0x3F80;
    }
    for (int i = tid; i < 15 * 64; i += 256) {
      int row = 65 + (i >> 6), col = i & 63;
      P_lds[row * LDK + col] = 0;
      V_lds[row * LDK + col] = 0;
    }
    __syncthreads();

    f32x4 acc_i[5];
#pragma unroll
    for (int n = 0; n < 5; ++n)
#pragma unroll
      for (int r = 0; r < 4; ++r) acc_i[n][r] = 0.f;
#pragma unroll
    for (int kk = 0; kk < 2; ++kk) {
      bf16x8 af = *reinterpret_cast<const bf16x8*>(&A_lds[(w * 16 + lr) * LDK + kk * 32 + lg * 8]);
#pragma unroll
      for (int n = 0; n < 5; ++n) {
        bf16x8 bfr = *reinterpret_cast<const bf16x8*>(&P_lds[(n * 16 + lr) * LDK + kk * 32 + lg * 8]);
        acc_i[n] = __builtin_amdgcn_mfma_f32_16x16x32_bf16(af, bfr, acc_i[n], 0, 0, 0);
      }
    }
    f32x4 acc_s[4];
#pragma unroll
    for (int n = 0; n < 4; ++n)
#pragma unroll
      for (int r = 0; r < 4; ++r) acc_s[n][r] = 0.f;
#pragma unroll
    for (int kk = 0; kk < 2; ++kk) {
      bf16x8 af = *reinterpret_cast<const bf16x8*>(&A_lds[(w * 16 + lr) * LDK + kk * 32 + lg * 8]);
#pragma unroll
      for (int n = 0; n < 4; ++n) {
        bf16x8 bfr = *reinterpret_cast<const bf16x8*>(&K_lds[(n * 16 + lr) * LDK + kk * 32 + lg * 8]);
        acc_s[n] = __builtin_amdgcn_mfma_f32_16x16x32_bf16(af, bfr, acc_s[n], 0, 0, 0);
      }
    }
#pragma unroll
    for (int n = 0; n < 4; ++n)
#pragma unroll
      for (int r = 0; r < 4; ++r) {
        int s_loc = w * 16 + lg * 4 + r, t = n * 16 + lr;
        float v = (t <= s_loc) ? acc_s[n][r] : 0.f;
        S_lds[s_loc * LDK + t] = f2bf(v);
      }
    __syncthreads();
    f32x4 acc_p[5];
#pragma unroll
    for (int n = 0; n < 5; ++n)
#pragma unroll
      for (int r = 0; r < 4; ++r) acc_p[n][r] = 0.f;
#pragma unroll
    for (int kk = 0; kk < 2; ++kk) {
      bf16x8 af = *reinterpret_cast<const bf16x8*>(&S_lds[(w * 16 + lr) * LDK + kk * 32 + lg * 8]);
#pragma unroll
      for (int n = 0; n < 5; ++n) {
        bf16x8 bfr = *reinterpret_cast<const bf16x8*>(&V_lds[(n * 16 + lr) * LDK + kk * 32 + lg * 8]);
        acc_p[n] = __builtin_amdgcn_mfma_f32_16x16x32_bf16(af, bfr, acc_p[n], 0, 0, 0);
      }
    }
#pragma unroll
    for (int r = 0; r < 4; ++r) {
      float den = acc_i[4][r] + acc_p[4][r];
      den = __shfl(den, lane & 48);
      den = fmaxf(den, EPSF);
      int s = sb + w * 16 + lg * 4 + r;
#pragma unroll
      for (int n = 0; n < 4; ++n)
        LOB[s * 1024 + h * 64 + n * 16 + lr] = f2bf((acc_i[n][r] + acc_p[n][r]) / den);
    }
  } else {
    int bb = b - 512;
    int m0 = (bb >> 1) * 128, n0 = (bb & 1) * 128;
    int wid = tid >> 6, lane = tid & 63;
    int wr = wid >> 1, wc = wid & 1;
    int lr = lane & 15, lg = lane >> 4;
    unsigned short* As = (unsigned short*)smem;
    unsigned short* Bs = (unsigned short*)(smem + 18432);

    f32x4 acc[4][4];
#pragma unroll
    for (int m = 0; m < 4; ++m)
#pragma unroll
      for (int n = 0; n < 4; ++n)
#pragma unroll
        for (int r = 0; r < 4; ++r) acc[m][n][r] = 0.f;

    for (int kt = 0; kt < 16; ++kt) {
      int k0 = kt * 64;
#pragma unroll
      for (int p = 0; p < 4; ++p) {
        int c = p * 256 + tid;
        int row = c >> 3, k8 = c & 7;
        u16x8 va = *reinterpret_cast<const u16x8*>(COB + (m0 + row) * 1024 + k0 + k8 * 8);
        *reinterpret_cast<u16x8*>(&As[row * LDK + k8 * 8]) = va;
        u16x8 vb = *reinterpret_cast<const u16x8*>(W1T + (n0 + row) * 1024 + k0 + k8 * 8);
        *reinterpret_cast<u16x8*>(&Bs[row * LDK + k8 * 8]) = vb;
      }
      __syncthreads();
#pragma unroll
      for (int kk = 0; kk < 2; ++kk) {
        bf16x8 af[4], bfr[4];
#pragma unroll
        for (int m = 0; m < 4; ++m)
          af[m] = *reinterpret_cast<const bf16x8*>(&As[(wr * 64 + m * 16 + lr) * LDK + kk * 32 + lg * 8]);
#pragma unroll
        for (int n = 0; n < 4; ++n)
          bfr[n] = *reinterpret_cast<const bf16x8*>(&Bs[(wc * 64 + n * 16 + lr) * LDK + kk * 32 + lg * 8]);
#pragma unroll
        for (int m = 0; m < 4; ++m)
#pragma unroll
          for (int n = 0; n < 4; ++n)
            acc[m][n] = __builtin_amdgcn_mfma_f32_16x16x32_bf16(af[m], bfr[n], acc[m][n], 0, 0, 0);
      }
      __syncthreads();
    }
#pragma unroll
    for (int m = 0; m < 4; ++m)
#pragma unroll
      for (int n = 0; n < 4; ++n)
#pragma unroll
        for (int r = 0; r < 4; ++r)
          H1[(m0 + wr * 64 + m * 16 + lg * 4 + r) * 256 + n0 + wc * 64 + n * 16 + lr] = acc[m][n][r];
  }
}

// ---------------- eg stage 2 ------------------------------------------------
__global__ __launch_bounds__(256) void eg_fin(const float* __restrict__ H1,
    const float* __restrict__ B1, const float* __restrict__ W2,
    const float* __restrict__ B2, float* __restrict__ EP)
{
  int wid = threadIdx.x >> 6, lane = threadIdx.x & 63;
  int s = blockIdx.x * 4 + wid;
  float4 h = *reinterpret_cast<const float4*>(H1 + s * 256 + lane * 4);
  float4 b = *reinterpret_cast<const float4*>(B1 + lane * 4);
  float4 w = *reinterpret_cast<const float4*>(W2 + lane * 4);
  float v = fmaxf(h.x + b.x, 0.f) * w.x + fmaxf(h.y + b.y, 0.f) * w.y
          + fmaxf(h.z + b.z, 0.f) * w.z + fmaxf(h.w + b.w, 0.f) * w.w;
  v = wave_allsum(v);
  if (lane == 0) EP[s] = 1.f / (1.f + expf(-(v + B2[0])));
}

// ---------------- fine retrieval + combine (weights fused), bf16 MFMA -------
__global__ __launch_bounds__(256) void fine_mfma(const unsigned short* __restrict__ SQB,
    const unsigned short* __restrict__ FMT, const float* __restrict__ RELS,
    const float* __restrict__ PARTS, const float* __restrict__ EP,
    const unsigned short* __restrict__ COB, unsigned short* __restrict__ MOB)
{
  int h = blockIdx.x, st = blockIdx.y;
  int tid = threadIdx.x;
  int w = tid >> 6, lane = tid & 63;
  int lr = lane & 15, lg = lane >> 4;
  int s0 = st * 128;

  __shared__ unsigned short A_lds[128 * LDK];
  __shared__ unsigned short B_lds[4 * 64 * LDK];
  __shared__ float rmean[4];
  if (tid < 4) {
    float s = 0.f;
    for (int t = 0; t < 32; ++t) s += PARTS[tid * 512 + h * 32 + t];
    rmean[tid] = s * (1.f / 2048.f);
  }

#pragma unroll
  for (int p = 0; p < 4; ++p) {
    int c = p * 256 + tid;
    int row = c >> 3, k8 = c & 7;
    *reinterpret_cast<u16x8*>(&A_lds[row * LDK + k8 * 8]) =
        *reinterpret_cast<const u16x8*>(SQB + (s0 + row) * 1024 + h * 64 + k8 * 8);
  }
#pragma unroll
  for (int p = 0; p < 8; ++p) {
    int c = p * 256 + tid;
    int f = c >> 9, rem = c & 511;
    int e = rem >> 3, k8 = rem & 7;
    *reinterpret_cast<u16x8*>(&B_lds[(f * 64 + e) * LDK + k8 * 8]) =
        *reinterpret_cast<const u16x8*>(FMT + (f * 16 + h) * 4096 + e * 64 + k8 * 8);
  }
  __syncthreads();

  f32x4 acc[4][2][4];
#pragma unroll
  for (int f = 0; f < 4; ++f)
#pragma unroll
    for (int m = 0; m < 2; ++m)
#pragma unroll
      for (int n = 0; n < 4; ++n)
#pragma unroll
        for (int r = 0; r < 4; ++r) acc[f][m][n][r] = 0.f;

#pragma unroll
  for (int kk = 0; kk < 2; ++kk) {
    bf16x8 af[2];
#pragma unroll
    for (int m = 0; m < 2; ++m)
      af[m] = *reinterpret_cast<const bf16x8*>(&A_lds[(w * 32 + m * 16 + lr) * LDK + kk * 32 + lg * 8]);
#pragma unroll
    for (int f = 0; f < 4; ++f) {
      bf16x8 bf4[4];
#pragma unroll
      for (int n = 0; n < 4; ++n)
        bf4[n] = *reinterpret_cast<const bf16x8*>(&B_lds[(f * 64 + n * 16 + lr) * LDK + kk * 32 + lg * 8]);
#pragma unroll
      for (int m = 0; m < 2; ++m)
#pragma unroll
        for (int n = 0; n < 4; ++n)
          acc[f][m][n] = __builtin_amdgcn_mfma_f32_16x16x32_bf16(af[m], bf4[n], acc[f][m][n], 0, 0, 0);
    }
  }

  float rm = fmaxf(fmaxf(rmean[0], rmean[1]), fmaxf(rmean[2], rmean[3]));
  float e0 = expf(rmean[0] - rm), e1 = expf(rmean[1] - rm);
  float e2 = expf(rmean[2] - rm), e3 = expf(rmean[3] - rm);
  float winv = 1.f / (e0 + e1 + e2 + e3);
  float w0 = e0 * winv, w1 = e1 * winv, w2 = e2 * winv, w3 = e3 * winv;

#pragma unroll
  for (int m = 0; m < 2; ++m)
#pragma unroll
    for (int r = 0; r < 4; ++r) {
      int s = s0 + w * 32 + m * 16 + lg * 4 + r;
      float e = EP[s];
      float i0 = w0 / fmaxf(RELS[0 * 32768 + h * 2048 + s], EPSF);
      float i1 = w1 / fmaxf(RELS[1 * 32768 + h * 2048 + s], EPSF);
      float i2 = w2 / fmaxf(RELS[2 * 32768 + h * 2048 + s], EPSF);
      float i3 = w3 / fmaxf(RELS[3 * 32768 + h * 2048 + s], EPSF);
#pragma unroll
      for (int n = 0; n < 4; ++n) {
        int dg = h * 64 + n * 16 + lr;
        float fine = acc[0][m][n][r] * i0 + acc[1][m][n][r] * i1
                   + acc[2][m][n][r] * i2 + acc[3][m][n][r] * i3;
        float cv = bf2f(COB[s * 1024 + dg]);
        MOB[s * 1024 + dg] = f2bf(e * fine + (1.f - e) * cv);
      }
    }
}

// final out-proj: A = gate-combined(mob, lob) computed during staging
__global__ __launch_bounds__(256) void mm_gate_bf16(const unsigned short* __restrict__ MOB,
    const unsigned short* __restrict__ LOB, const float* __restrict__ MG,
    const unsigned short* __restrict__ BT, float* __restrict__ C)
{
  __shared__ unsigned short As[128 * LDK];
  __shared__ unsigned short Bs[128 * LDK];
  __shared__ float gs[16];
  int tid = threadIdx.x;
  int m0 = blockIdx.y * 128, n0 = blockIdx.x * 128;
  int wid = tid >> 6, lane = tid & 63;
  int wr = wid >> 1, wc = wid & 1;
  int lr = lane & 15, lg = lane >> 4;
  if (tid < 16) gs[tid] = 1.f / (1.f + expf(-MG[tid]));
  __syncthreads();

  f32x4 acc[4][4];
#pragma unroll
  for (int m = 0; m < 4; ++m)
#pragma unroll
    for (int n = 0; n < 4; ++n)
#pragma unroll
      for (int r = 0; r < 4; ++r) acc[m][n][r] = 0.f;

  for (int kt = 0; kt < 16; ++kt) {
    int k0 = kt * 64;
#pragma unroll
    for (int p = 0; p < 4; ++p) {
      int c = p * 256 + tid;
      int row = c >> 3, k8 = c & 7;
      int col = k0 + k8 * 8;
      float g = gs[col >> 6];
      u16x8 mv = *reinterpret_cast<const u16x8*>(MOB + (m0 + row) * 1024 + col);
      u16x8 lv = *reinterpret_cast<const u16x8*>(LOB + (m0 + row) * 1024 + col);
      u16x8 o;
#pragma unroll
      for (int j = 0; j < 8; ++j)
        o[j] = f2bf(g * bf2f((unsigned short)mv[j]) + (1.f - g) * bf2f((unsigned short)lv[j]));
      *reinterpret_cast<u16x8*>(&As[row * LDK + k8 * 8]) = o;
      u16x8 vb = *reinterpret_cast<const u16x8*>(BT + (n0 + row) * 1024 + k0 + k8 * 8);
      *reinterpret_cast<u16x8*>(&Bs[row * LDK + k8 * 8]) = vb;
    }
    __syncthreads();
#pragma unroll
    for (int kk = 0; kk < 2; ++kk) {
      bf16x8 af[4], bfr[4];
#pragma unroll
      for (int m = 0; m < 4; ++m)
        af[m] = *reinterpret_cast<const bf16x8*>(&As[(wr * 64 + m * 16 + lr) * LDK + kk * 32 + lg * 8]);
#pragma unroll
      for (int n = 0; n < 4; ++n)
        bfr[n] = *reinterpret_cast<const bf16x8*>(&Bs[(wc * 64 + n * 16 + lr) * LDK + kk * 32 + lg * 8]);
#pragma unroll
      for (int m = 0; m < 4; ++m)
#pragma unroll
        for (int n = 0; n < 4; ++n)
          acc[m][n] = __builtin_amdgcn_mfma_f32_16x16x32_bf16(af[m], bfr[n], acc[m][n], 0, 0, 0);
    }
    __syncthreads();
  }
#pragma unroll
  for (int m = 0; m < 4; ++m)
#pragma unroll
    for (int n = 0; n < 4; ++n)
#pragma unroll
      for (int r = 0; r < 4; ++r)
        C[(m0 + wr * 64 + m * 16 + lg * 4 + r) * 1024 + n0 + wc * 64 + n * 16 + lr] = acc[m][n][r];
}

// ---------------------------------------------------------------------------
extern "C" void kernel_launch(void* const* d_in, const int* in_sizes, int n_in,
                              void* d_out, int out_size, void* d_ws, size_t ws_size,
                              hipStream_t stream)
{
  const float* hs   = (const float*)d_in[0];
  const float* wq   = (const float*)d_in[1];
  const float* wk   = (const float*)d_in[2];
  const float* wv   = (const float*)d_in[3];
  const float* wo   = (const float*)d_in[4];
  const float* mg   = (const float*)d_in[5];
  const float* egw1 = (const float*)d_in[6];
  const float* egb1 = (const float*)d_in[7];
  const float* egw2 = (const float*)d_in[8];
  const float* egb2 = (const float*)d_in[9];
  const float* fm   = (const float*)d_in[10];
  const float* fn   = (const float*)d_in[11];
  float* out = (float*)d_out;

  // ---- disjoint workspace layout ----
  float* ws     = (float*)d_ws;
  float* zc     = ws;                       // 1024
  float* rels   = zc + 1024;                // 131072
  float* parts  = rels + 131072;            // 2048
  float* ep     = parts + 2048;             // 2048
  float* relc   = ep + 2048;                // 32768
  float* states = relc + 32768;             // 2129920
  float* h1     = states + 2129920;         // 524288
  unsigned short* hsb  = (unsigned short*)(h1 + 524288);   // 2097152 each
  unsigned short* sqb  = hsb + 2097152;
  unsigned short* skb  = sqb + 2097152;
  unsigned short* vvb  = skb + 2097152;
  unsigned short* cob  = vvb + 2097152;
  unsigned short* mob  = cob + 2097152;
  unsigned short* lob  = mob + 2097152;
  unsigned short* wqT  = lob + 2097152;     // 1048576 each
  unsigned short* wkT  = wqT + 1048576;
  unsigned short* wvT  = wkT + 1048576;
  unsigned short* woT  = wvT + 1048576;
  unsigned short* w1T  = woT + 1048576;     // 262144
  unsigned short* fmbT = w1T + 262144;      // 262144
  unsigned short* mcT  = fmbT + 262144;     // 65536
  unsigned short* statesb = mcT + 65536;    // 2129920

  prep_kernel<<<3264, 256, 0, stream>>>(fm, fn, hs, wq, wk, wv, wo, egw1,
      mcT, zc, wqT, wkT, wvT, woT, w1T, fmbT, hsb);
  proj_bf16<<<dim3(8, 16, 3), 256, 0, stream>>>(hsb, wqT, wkT, wvT, sqb, skb, vvb);
  mid1_kernel<<<1024, 256, 0, stream>>>(sqb, zc, fn, skb, vvb, relc, rels, parts, states);
  mid2_kernel<<<516, 256, 0, stream>>>(sqb, mcT, relc, states, cob, statesb);
  mid3_kernel<<<544, 256, 0, stream>>>(sqb, skb, vvb, statesb, cob, w1T, lob, h1);
  eg_fin<<<512, 256, 0, stream>>>(h1, egb1, egw2, egb2, ep);
  fine_mfma<<<dim3(16, 16), 256, 0, stream>>>(sqb, fmbT, rels, parts, ep, cob, mob);
  mm_gate_bf16<<<dim3(8, 16), 256, 0, stream>>>(mob, lob, mg, woT, out);
}